// Round 1
// baseline (264.363 us; speedup 1.0000x reference)
//
#include <hip/hip_runtime.h>

// PointPillars BEV scatter — gather formulation v2.
// Change vs v1: channel dimension spread across threads (256 threads =
// 64 cells x 16 channel-quads), map staged via LDS, 4 loads + 4 stores
// per thread. 13392 blocks (~52/CU) for latency hiding; every feature
// line is consumed by a single load instruction (no L1 temporal reuse
// needed); stores remain 256B-contiguous per 16-lane group.
// Output layout: (B, C, H, W) fp32.

#define BEV_H 496
#define BEV_W 432
#define BB 4
#define CC 64
#define HW (BEV_H * BEV_W)              // 214272 (divisible by 64)
#define CELLS_PER_BLOCK 64
#define NBLOCKS (BB * HW / CELLS_PER_BLOCK)  // 13392 (exact)

// Step 2: scatter pillar index m into the (B,H,W) map. Map pre-set to -1.
__global__ __launch_bounds__(256) void scatter_idx_kernel(
    const int* __restrict__ coords, int* __restrict__ map, int M) {
  int m = blockIdx.x * 256 + threadIdx.x;
  if (m >= M) return;
  int b = coords[3 * m + 0];
  int y = coords[3 * m + 1];
  int x = coords[3 * m + 2];
  map[(b * BEV_H + y) * BEV_W + x] = m;
}

// Step 3: block = 64 consecutive cells (16 quads) x 64 channels.
// Thread tid = c4*16 + q: loads rows m[4q..4q+3] at channel-quad c4
// (4 x float4 = bytes [c4*16, c4*16+16) of each row; the 4 lanes sharing
// q across c4 0..3 cover one full 64B line per row), transposes 4x4 in
// registers, stores 4 float4 into channel planes c = 4*c4+k.
// Store instruction k: lanes q=0..15 per c4-group -> 256B contiguous.
__global__ __launch_bounds__(256) void gather_kernel(
    const int* __restrict__ map, const float4* __restrict__ feat4,
    float4* __restrict__ out4) {
  __shared__ int smap[CELLS_PER_BLOCK];
  const int cellbase = blockIdx.x * CELLS_PER_BLOCK;  // multiple of 64
  const int tid = threadIdx.x;

  if (tid < CELLS_PER_BLOCK) smap[tid] = map[cellbase + tid];
  __syncthreads();

  const int c4 = tid >> 4;   // [0,16) channel-quad
  const int q  = tid & 15;   // [0,16) cell-quad within block

  const int m0 = smap[4 * q + 0];
  const int m1 = smap[4 * q + 1];
  const int m2 = smap[4 * q + 2];
  const int m3 = smap[4 * q + 3];

  const float4 z = make_float4(0.f, 0.f, 0.f, 0.f);
  float4 a0 = (m0 < 0) ? z : feat4[(size_t)m0 * (CC / 4) + c4];
  float4 a1 = (m1 < 0) ? z : feat4[(size_t)m1 * (CC / 4) + c4];
  float4 a2 = (m2 < 0) ? z : feat4[(size_t)m2 * (CC / 4) + c4];
  float4 a3 = (m3 < 0) ? z : feat4[(size_t)m3 * (CC / 4) + c4];

  // Output float4 index for (b, c, hw): (b*CC + c)*(HW/4) + hw/4.
  const int b = cellbase / HW;                 // uniform per block
  const int hwq = (cellbase - b * HW) >> 2;    // quad index of block base
  const size_t obase =
      (size_t)b * CC * (HW / 4) + (size_t)hwq + q + (size_t)(4 * c4) * (HW / 4);

  out4[obase + 0 * (size_t)(HW / 4)] = make_float4(a0.x, a1.x, a2.x, a3.x);
  out4[obase + 1 * (size_t)(HW / 4)] = make_float4(a0.y, a1.y, a2.y, a3.y);
  out4[obase + 2 * (size_t)(HW / 4)] = make_float4(a0.z, a1.z, a2.z, a3.z);
  out4[obase + 3 * (size_t)(HW / 4)] = make_float4(a0.w, a1.w, a2.w, a3.w);
}

extern "C" void kernel_launch(void* const* d_in, const int* in_sizes, int n_in,
                              void* d_out, int out_size, void* d_ws, size_t ws_size,
                              hipStream_t stream) {
  const int*   coords = (const int*)d_in[0];    // (M, 3) int32
  const float* feat   = (const float*)d_in[1];  // (M, 64) fp32
  float*       out    = (float*)d_out;          // (4, 64, 496, 432) fp32
  int M = in_sizes[0] / 3;

  int* map = (int*)d_ws;  // (B, H, W) int32 index map, 3.43 MB

  // Step 1: map = -1 everywhere (0xFF bytes). Stream-ordered, graph-safe.
  hipMemsetAsync(map, 0xFF, (size_t)BB * HW * sizeof(int), stream);

  scatter_idx_kernel<<<(M + 255) / 256, 256, 0, stream>>>(coords, map, M);

  gather_kernel<<<NBLOCKS, 256, 0, stream>>>(
      map, (const float4*)feat, (float4*)out);
}

// Round 2
// 259.345 us; speedup vs baseline: 1.0194x; 1.0194x over previous
//
#include <hip/hip_runtime.h>

// PointPillars BEV scatter — gather formulation v3.
// Model (post-mortem r1): timed window ~= harness fill (~140us) + restore
// overhead (~70us) + ours (~50us vs ~42us traffic floor). This version
// shaves the controllable part: no LDS/barrier in gather (broadcast int4
// map reads), nontemporal out stores + feat loads (don't churn 219MB
// through L2), coalesced coords staging in scatter.
// Output layout: (B, C, H, W) fp32.

#define BEV_H 496
#define BEV_W 432
#define BB 4
#define CC 64
#define HW (BEV_H * BEV_W)              // 214272; HW/64 = 3348
#define CELLS_PER_BLOCK 64
#define NBLOCKS (BB * HW / CELLS_PER_BLOCK)  // 13392 (exact)
#define BLOCKS_PER_B (HW / CELLS_PER_BLOCK)  // 3348

typedef float f4 __attribute__((ext_vector_type(4)));
typedef int i4 __attribute__((ext_vector_type(4)));

// Step 2: scatter pillar index m into the (B,H,W) map. Map pre-set to -1.
// Coords staged through LDS so global loads are 3 contiguous wave-loads
// (stride-3 LDS read = all 32 banks covered, 2-way alias = free).
__global__ __launch_bounds__(256) void scatter_idx_kernel(
    const int* __restrict__ coords, int* __restrict__ map, int M) {
  __shared__ int sc[3 * 256];
  const int base = blockIdx.x * (3 * 256);
  const int lim = 3 * M;
#pragma unroll
  for (int k = 0; k < 3; ++k) {
    int idx = base + k * 256 + threadIdx.x;
    sc[k * 256 + threadIdx.x] = (idx < lim) ? coords[idx] : 0;
  }
  __syncthreads();
  int m = blockIdx.x * 256 + threadIdx.x;
  if (m >= M) return;
  int b = sc[3 * threadIdx.x + 0];
  int y = sc[3 * threadIdx.x + 1];
  int x = sc[3 * threadIdx.x + 2];
  map[(b * BEV_H + y) * BEV_W + x] = m;
}

// Step 3: block = 64 consecutive cells (16 quads) x 64 channels.
// Thread tid = c4*16 + q handles cell-quad q at channel-quad c4:
// 4 nontemporal 16B feat loads (the 4 lanes sharing q across adjacent c4
// consume full 64B lines within one instruction), 4x4 register transpose,
// 4 nontemporal 16B stores (16-lane groups -> 256B contiguous segments).
__global__ __launch_bounds__(256) void gather_kernel(
    const i4* __restrict__ map4, const f4* __restrict__ feat4,
    f4* __restrict__ out4) {
  const int tid = threadIdx.x;
  const int c4 = tid >> 4;   // [0,16) channel-quad
  const int q  = tid & 15;   // [0,16) cell-quad within block

  // 16 lanes per q-group read the same int4 (broadcast); per wave: 16
  // distinct int4 = 256B; all 4 waves hit the same 256B in L1.
  i4 mi = map4[(size_t)blockIdx.x * 16 + q];
  const int m0 = mi.x, m1 = mi.y, m2 = mi.z, m3 = mi.w;
  const bool e0 = m0 < 0, e1 = m1 < 0, e2 = m2 < 0, e3 = m3 < 0;

  const f4* p0 = feat4 + (size_t)(e0 ? 0 : m0) * (CC / 4) + c4;
  const f4* p1 = feat4 + (size_t)(e1 ? 0 : m1) * (CC / 4) + c4;
  const f4* p2 = feat4 + (size_t)(e2 ? 0 : m2) * (CC / 4) + c4;
  const f4* p3 = feat4 + (size_t)(e3 ? 0 : m3) * (CC / 4) + c4;
  f4 a0 = __builtin_nontemporal_load(p0);
  f4 a1 = __builtin_nontemporal_load(p1);
  f4 a2 = __builtin_nontemporal_load(p2);
  f4 a3 = __builtin_nontemporal_load(p3);
  const f4 z = {0.f, 0.f, 0.f, 0.f};
  if (e0) a0 = z;
  if (e1) a1 = z;
  if (e2) a2 = z;
  if (e3) a3 = z;

  // Output float4 index for (b, c, hw): (b*CC + c)*(HW/4) + hw/4.
  const int b = blockIdx.x / BLOCKS_PER_B;               // uniform per block
  const int hwq = (blockIdx.x - b * BLOCKS_PER_B) * 16 + q;
  const size_t plane = (size_t)(HW / 4);
  f4* o = out4 + (size_t)b * CC * plane + (size_t)(4 * c4) * plane + hwq;

  f4 t0 = {a0.x, a1.x, a2.x, a3.x};
  f4 t1 = {a0.y, a1.y, a2.y, a3.y};
  f4 t2 = {a0.z, a1.z, a2.z, a3.z};
  f4 t3 = {a0.w, a1.w, a2.w, a3.w};
  __builtin_nontemporal_store(t0, o + 0 * plane);
  __builtin_nontemporal_store(t1, o + 1 * plane);
  __builtin_nontemporal_store(t2, o + 2 * plane);
  __builtin_nontemporal_store(t3, o + 3 * plane);
}

extern "C" void kernel_launch(void* const* d_in, const int* in_sizes, int n_in,
                              void* d_out, int out_size, void* d_ws, size_t ws_size,
                              hipStream_t stream) {
  const int*   coords = (const int*)d_in[0];    // (M, 3) int32
  const float* feat   = (const float*)d_in[1];  // (M, 64) fp32
  float*       out    = (float*)d_out;          // (4, 64, 496, 432) fp32
  int M = in_sizes[0] / 3;

  int* map = (int*)d_ws;  // (B, H, W) int32 index map, 3.43 MB

  // Step 1: map = -1 everywhere (0xFF bytes). Stream-ordered, graph-safe.
  hipMemsetAsync(map, 0xFF, (size_t)BB * HW * sizeof(int), stream);

  scatter_idx_kernel<<<(M + 255) / 256, 256, 0, stream>>>(coords, map, M);

  gather_kernel<<<NBLOCKS, 256, 0, stream>>>(
      (const i4*)map, (const f4*)feat, (f4*)out);
}